// Round 4
// baseline (108.750 us; speedup 1.0000x reference)
//
#include <hip/hip_runtime.h>

// Overlapped-chunk HMM forward filter, all-VALU inner loop, ILP=2.
// Each 16-lane group runs TWO chunks (c, c+npairs) interleaved; each chunk owns
// CHUNK_L timesteps and warm-starts WARMUP_W steps early from pi (filter
// contraction kills the init error; W=48 measured at noise floor in R2/R3).
// Dot products use v_fmac_f32_dpp row_newbcast (single-accumulator form so the
// DPP-combine pass can fold the movs); normalizer via DPP row_ror reduction.
// Warm-up runs the unnormalized linear recurrence (scale-invariant), renorming
// once per 4-step block. y is software-pipelined one float4 block ahead.
#define CHUNK_L 32
#define WARMUP_W 48

template<int K> __device__ __forceinline__ float bcast16(float v) {
    // broadcast lane (row_start + K) across the 16-lane row (row_newbcast)
    return __int_as_float(__builtin_amdgcn_update_dpp(
        0, __float_as_int(v), 0x150 | K, 0xF, 0xF, true));
}
template<int N> __device__ __forceinline__ float rowror16(float v) {
    return __int_as_float(__builtin_amdgcn_update_dpp(
        0, __float_as_int(v), 0x120 | N, 0xF, 0xF, true));
}

// (alpha @ P)_j : single-accumulator fmac chain -> v_fmac_f32_dpp foldable
__device__ __forceinline__ float dot16(float a, const float pc[16]) {
    float u = bcast16<0>(a) * pc[0];
    u = fmaf(bcast16<1>(a),  pc[1],  u);
    u = fmaf(bcast16<2>(a),  pc[2],  u);
    u = fmaf(bcast16<3>(a),  pc[3],  u);
    u = fmaf(bcast16<4>(a),  pc[4],  u);
    u = fmaf(bcast16<5>(a),  pc[5],  u);
    u = fmaf(bcast16<6>(a),  pc[6],  u);
    u = fmaf(bcast16<7>(a),  pc[7],  u);
    u = fmaf(bcast16<8>(a),  pc[8],  u);
    u = fmaf(bcast16<9>(a),  pc[9],  u);
    u = fmaf(bcast16<10>(a), pc[10], u);
    u = fmaf(bcast16<11>(a), pc[11], u);
    u = fmaf(bcast16<12>(a), pc[12], u);
    u = fmaf(bcast16<13>(a), pc[13], u);
    u = fmaf(bcast16<14>(a), pc[14], u);
    u = fmaf(bcast16<15>(a), pc[15], u);
    return u;
}

__device__ __forceinline__ float rowsum16(float p) {
    p += rowror16<1>(p);
    p += rowror16<2>(p);
    p += rowror16<4>(p);
    p += rowror16<8>(p);
    return p;
}

__global__ __launch_bounds__(256) void hmm_filter_kernel(
    const float* __restrict__ y,
    const float* __restrict__ logits,
    const float* __restrict__ mu,
    const float* __restrict__ log_sigma,
    float* __restrict__ out,
    int T, int nchunks, int npairs)
{
    __shared__ float Plds[256];
    __shared__ float Ba[256];
    __shared__ float Bb[256];

    const int tid = (int)threadIdx.x;
    const int j   = tid & 15;     // state / column index
    const int g   = tid >> 4;     // row (preamble) / group id (main)

    // ---- P = softmax(logits, axis=-1) ----
    float l = logits[tid];
    float m = l;
    #pragma unroll
    for (int s = 1; s < 16; s <<= 1) m = fmaxf(m, __shfl_xor(m, s, 16));
    float e = __expf(l - m);
    float rs = e;
    #pragma unroll
    for (int s = 1; s < 16; s <<= 1) rs += __shfl_xor(rs, s, 16);
    float Pv = e / rs;
    Plds[tid] = Pv;
    Ba[tid]   = Pv;
    __syncthreads();

    // ---- stationary pi: P^(2^10) via renormalized squaring (cold) ----
    float* cur = Ba;
    float* nxt = Bb;
    for (int itq = 0; itq < 10; ++itq) {
        float acc = 0.f;
        #pragma unroll
        for (int k = 0; k < 16; ++k)
            acc += cur[g * 16 + k] * cur[k * 16 + j];
        float rsum = acc;
        #pragma unroll
        for (int s = 1; s < 16; s <<= 1) rsum += __shfl_xor(rsum, s, 16);
        nxt[tid] = acc / rsum;
        __syncthreads();
        float* tmp = cur; cur = nxt; nxt = tmp;
    }
    // no barriers below this point (early returns are safe)

    const float api = cur[j];                 // pi_j

    float pc[16];
    #pragma unroll
    for (int k = 0; k < 16; ++k) pc[k] = Plds[k * 16 + j];

    const float muj = mu[j];
    const float isj = __expf(-log_sigma[j]);              // 1/sigma_j
    const float cfj = 0.3989422804014327f * isj;          // 1/(sigma*sqrt(2pi))
    const float nmj = -muj * isj;                         // z = fma(y, isj, nmj)
    const float lcf = __log2f(cfj);                       // log2(coef)
    const float K2  = -0.7213475204444817f;               // -0.5*log2(e)
    // g_j(y) = exp2( fma(z*z, K2, lcf) )

    const int pair = (int)blockIdx.x * 16 + g;
    if (pair >= npairs) return;
    const int cA = pair;
    int cB = pair + npairs;
    const bool hasB = (cB < nchunks);
    if (!hasB) cB = cA;                       // harmless duplicate; stores gated

    const int wfA = cA * CHUNK_L;
    const int wfB = cB * CHUNK_L;
    int tA = wfA - WARMUP_W; if (tA < 0) tA = 0;   // clamped chunks: EXACT from t=0
    int tB = wfB - WARMUP_W; if (tB < 0) tB = 0;

    float aA = api, aB = api;

    // unnormalized warm-up step: b <- g(t) * (b @ P)
    auto wstep = [&](float a, float yt) -> float {
        float up = dot16(a, pc);
        float z  = fmaf(yt, isj, nmj);
        float gj = exp2f(fmaf(z * z, K2, lcf));
        return up * gj;
    };
    auto renorm = [&](float a) -> float {
        float s = rowsum16(a);
        return a * __builtin_amdgcn_rcpf(s);
    };

    // ---- phase 1: equalize warm-up lengths (rare: only clamped chains) ----
    int wlA = wfA - tA;                       // in {0, 32, 48} (mult of 4)
    int wlB = wfB - tB;
    while (wlA > wlB) {
        const float4 y4 = *(const float4*)(y + tA);
        aA = wstep(aA, y4.x); aA = wstep(aA, y4.y);
        aA = wstep(aA, y4.z); aA = wstep(aA, y4.w);
        aA = renorm(aA); tA += 4; wlA -= 4;
    }
    while (wlB > wlA) {
        const float4 y4 = *(const float4*)(y + tB);
        aB = wstep(aB, y4.x); aB = wstep(aB, y4.y);
        aB = wstep(aB, y4.z); aB = wstep(aB, y4.w);
        aB = renorm(aB); tB += 4; wlB -= 4;
    }

    // ---- phase 2: interleaved warm-up, y pipelined one block ahead ----
    const int nb2 = wlA >> 2;
    if (nb2 > 0) {
        float4 cA4 = *(const float4*)(y + tA);
        float4 cB4 = *(const float4*)(y + tB);
        for (int b = 0; b < nb2; ++b) {
            // last iter prefetches y[wf..wf+3]: valid (first main block)
            const float4 nA4 = *(const float4*)(y + tA + 4);
            const float4 nB4 = *(const float4*)(y + tB + 4);
            aA = wstep(aA, cA4.x); aB = wstep(aB, cB4.x);
            aA = wstep(aA, cA4.y); aB = wstep(aB, cB4.y);
            aA = wstep(aA, cA4.z); aB = wstep(aB, cB4.z);
            aA = wstep(aA, cA4.w); aB = wstep(aB, cB4.w);
            aA = renorm(aA); aB = renorm(aB);
            tA += 4; tB += 4;
            cA4 = nA4; cB4 = nB4;
        }
    }

    // ---- phase 3: main chunks, both chains emit ----
    const int TN  = T * 16;
    const int Tm4 = T - 4;
    int oA = (tA << 4) + j;                   // Ut offset; Un at TN+o; Ft at 2*TN+t
    int oB = (tB << 4) + j;

    // normalized step with stores
    auto mstep = [&](float a, float yt, int off, bool en, float& sOut) -> float {
        float up = dot16(a, pc);
        float z  = fmaf(yt, isj, nmj);
        float gj = exp2f(fmaf(z * z, K2, lcf));
        float p  = up * gj;
        float s  = rowsum16(p);
        float an = p * __builtin_amdgcn_rcpf(s);
        if (en) {
            out[off]      = up;
            out[TN + off] = an;
        }
        sOut = s;
        return an;
    };

    float4 cA4 = *(const float4*)(y + tA);    // reload (phase-2 may have been empty)
    float4 cB4 = *(const float4*)(y + tB);
    #pragma unroll 1
    for (int b = 0; b < (CHUNK_L / 4); ++b) {
        const int pA = (tA + 4 < Tm4) ? (tA + 4) : Tm4;
        const int pB = (tB + 4 < Tm4) ? (tB + 4) : Tm4;
        const float4 nA4 = *(const float4*)(y + pA);
        const float4 nB4 = *(const float4*)(y + pB);
        float sA0, sA1, sA2, sA3, sB0, sB1, sB2, sB3;
        aA = mstep(aA, cA4.x, oA +  0, true,  sA0);
        aB = mstep(aB, cB4.x, oB +  0, hasB,  sB0);
        aA = mstep(aA, cA4.y, oA + 16, true,  sA1);
        aB = mstep(aB, cB4.y, oB + 16, hasB,  sB1);
        aA = mstep(aA, cA4.z, oA + 32, true,  sA2);
        aB = mstep(aB, cB4.z, oB + 32, hasB,  sB2);
        aA = mstep(aA, cA4.w, oA + 48, true,  sA3);
        aB = mstep(aB, cB4.w, oB + 48, hasB,  sB3);
        if (j == 0) {
            *(float4*)(out + 2 * TN + tA) = make_float4(sA0, sA1, sA2, sA3);
            if (hasB) *(float4*)(out + 2 * TN + tB) = make_float4(sB0, sB1, sB2, sB3);
        }
        tA += 4; tB += 4; oA += 64; oB += 64;
        cA4 = nA4; cB4 = nB4;
    }
}

extern "C" void kernel_launch(void* const* d_in, const int* in_sizes, int n_in,
                              void* d_out, int out_size, void* d_ws, size_t ws_size,
                              hipStream_t stream) {
    const float* y      = (const float*)d_in[0];
    const float* logits = (const float*)d_in[1];
    const float* mu     = (const float*)d_in[2];
    const float* ls     = (const float*)d_in[3];
    float* out = (float*)d_out;
    const int T = in_sizes[0];                 // 500000 = 32 * 15625 (exact chunks)

    const int nchunks = (T + CHUNK_L - 1) / CHUNK_L;
    const int npairs  = (nchunks + 1) / 2;
    const int blocks  = (npairs + 15) / 16;
    hmm_filter_kernel<<<blocks, 256, 0, stream>>>(y, logits, mu, ls, out,
                                                  T, nchunks, npairs);
}